// Round 8
// baseline (162.646 us; speedup 1.0000x reference)
//
#include <hip/hip_runtime.h>
#include <cstdint>
#include <cstddef>

#define MROWS 1024
#define NCOLS 4096
#define TOPK 8
#define NKEYS (MROWS * TOPK)   // 8192

typedef unsigned long long u64;

// key = (p_bits << 22) | ((1023-row) << 12) | (4095-col)
// u64 descending == p desc, then row asc, then col asc (flat-index tie-break).
__device__ inline int key_col(u64 k) { return (NCOLS - 1) - (int)(k & 0xFFFull); }
__device__ inline int key_row(u64 k) { return (MROWS - 1) - (int)((k >> 12) & 0x3FFull); }

// single-wave LDS ordering fence: wait LDS only, do NOT drain vmcnt
#define WAVE_FENCE() __asm__ volatile("s_waitcnt lgkmcnt(0)" ::: "memory")

__device__ inline float wave_sum_f(float v) {
    #pragma unroll
    for (int off = 32; off >= 1; off >>= 1)
        v += __shfl_xor(v, off, 64);
    return v;
}
__device__ inline u64 wave_max_u64(u64 v) {
    #pragma unroll
    for (int off = 32; off >= 1; off >>= 1) {
        u64 o = __shfl_xor(v, off, 64);
        v = o > v ? o : v;
    }
    return v;
}
__device__ inline u64 umax64(u64 a, u64 b) { return a > b ? a : b; }

// ---------------- K1: partial exp-sums (no max shift) + bitmap + counter -------
// exp(s)/sum(exp(s)) == softmax(s) to ~2 ulps; the uniform 1/gsum scale cannot
// reorder keys, and candidate s-gaps are ~8000 ulps, so assignment is exact.
__global__ __launch_bounds__(256) void k_sum(const float* __restrict__ s,
                                             float* __restrict__ bsum,
                                             unsigned* __restrict__ bitmap,
                                             unsigned* __restrict__ counter,
                                             const int* __restrict__ cont,
                                             const int* __restrict__ prev) {
    int b = blockIdx.x, t = threadIdx.x;
    __shared__ float fred[4];
    if (b == 0) {
        if (t < 128) bitmap[t] = 0u;
        if (t == 0) counter[0] = 0u;
    }
    const float4* s4 = (const float4*)s;
    int base = b * 4096 + t;
    float acc = 0.0f;
    #pragma unroll
    for (int i = 0; i < 16; ++i) {
        float4 v = s4[base + i * 256];
        acc += expf(v.x) + expf(v.y) + expf(v.z) + expf(v.w);
    }
    acc = wave_sum_f(acc);
    if ((t & 63) == 0) fred[t >> 6] = acc;
    __syncthreads();
    if (t == 0) bsum[b] = fred[0] + fred[1] + fred[2] + fred[3];
    if (b == 0) {
        // barrier above ordered bitmap zeroing before these atomics
        for (int i = t; i < MROWS; i += 256) {
            if (cont[i]) {
                int c = prev[i];
                atomicOr(&bitmap[c >> 5], 1u << (c & 31));
            }
        }
    }
}

// ---------------- K2: policy + register top-8 + last-block dominant match ------
__global__ __launch_bounds__(256) void k_fused(const float* __restrict__ s,
                                               const float* __restrict__ bsum,
                                               const unsigned* __restrict__ bitmap,
                                               const int* __restrict__ cont,
                                               const int* __restrict__ prev,
                                               float* __restrict__ policy,
                                               u64* __restrict__ keys8,
                                               unsigned* __restrict__ counter,
                                               float* __restrict__ actions) {
    __shared__ u64 lds_u64[NCOLS];             // colbest in match phase (32 KiB)
    __shared__ float fred[4];
    __shared__ u64 red[4];
    __shared__ unsigned coldone[NCOLS / 32];   // 128
    __shared__ unsigned rowdone[MROWS / 32];   // 32
    __shared__ float act[MROWS];               // 4 KiB
    __shared__ int exh_flag;
    __shared__ int is_last;

    int r = blockIdx.x, t = threadIdx.x;

    // ---- gsum from block partials ----
    float sv = bsum[t];
    sv = wave_sum_f(sv);
    if ((t & 63) == 0) fred[t >> 6] = sv;
    __syncthreads();
    float inv = 1.0f / (fred[0] + fred[1] + fred[2] + fred[3]);

    // ---- policy write + per-thread keys in registers ----
    int cg_ = cont[r];
    const float4* s4 = (const float4*)(s + (size_t)r * NCOLS);
    float4* p4 = (float4*)(policy + (size_t)r * NCOLS);
    u64 rowpart = (u64)(MROWS - 1 - r) << 12;
    u64 mykeys[16];
    #pragma unroll
    for (int i = 0; i < 4; ++i) {
        int f = t + i * 256;
        float4 v = s4[f];
        float4 pv;
        pv.x = expf(v.x) * inv;
        pv.y = expf(v.y) * inv;
        pv.z = expf(v.z) * inv;
        pv.w = expf(v.w) * inv;
        p4[f] = pv;
        int c0 = 4 * f;
        unsigned bmw = bitmap[c0 >> 5];
        float pe[4] = {pv.x, pv.y, pv.z, pv.w};
        #pragma unroll
        for (int e = 0; e < 4; ++e) {
            int c = c0 + e;
            u64 kk = 0ull;
            if (!cg_ && !((bmw >> (c & 31)) & 1u))
                kk = ((u64)__float_as_uint(pe[e]) << 22) | rowpart | (u64)(NCOLS - 1 - c);
            mykeys[i * 4 + e] = kk;
        }
    }

    // ---- top-8 extraction: register-cached per-thread max, block reduce ----
    u64 tmax = 0ull;
    #pragma unroll
    for (int k = 0; k < 16; ++k) tmax = umax64(tmax, mykeys[k]);
    for (int pass = 0; pass < TOPK; ++pass) {
        u64 best = wave_max_u64(tmax);
        if ((t & 63) == 0) red[t >> 6] = best;
        __syncthreads();
        best = umax64(umax64(red[0], red[1]), umax64(red[2], red[3]));
        if (t == 0) keys8[(size_t)r * TOPK + pass] = best;   // 0 for cg_ rows
        if (tmax == best && best != 0ull) {   // unique winner (keys distinct)
            #pragma unroll
            for (int k = 0; k < 16; ++k)
                if (mykeys[k] == best) mykeys[k] = 0ull;
            tmax = 0ull;
            #pragma unroll
            for (int k = 0; k < 16; ++k) tmax = umax64(tmax, mykeys[k]);
        }
        __syncthreads();   // red[] reuse next pass
    }

    // ---- last-block handoff ----
    __threadfence();   // release: keys8 + policy visible device-wide
    if (t == 0) is_last = (atomicAdd(counter, 1u) == (unsigned)(gridDim.x - 1));
    __syncthreads();
    if (!is_last) return;
    __threadfence();   // acquire: observe all other blocks' stores

    // ================= MATCH: parallel dominant-edge (exact greedy) ==========
    u64* colbest = lds_u64;
    #pragma unroll
    for (int i = 0; i < 16; ++i) colbest[t + i * 256] = 0ull;
    if (t < 128) coldone[t] = bitmap[t];
    if (t < 32) rowdone[t] = 0u;
    if (t == 0) exh_flag = 0;
    __syncthreads();

    u64 myk[4][TOPK];
    bool active[4];
    #pragma unroll
    for (int q = 0; q < 4; ++q) {
        int rr = t + q * 256;
        int cgf = cont[rr];
        act[rr] = cgf ? (float)prev[rr] : -1.0f;
        active[q] = (cgf == 0);
        if (cgf) atomicOr(&rowdone[rr >> 5], 1u << (rr & 31));
        const u64* gk = keys8 + (size_t)rr * TOPK;
        #pragma unroll
        for (int k = 0; k < TOPK; ++k) myk[q][k] = gk[k];
    }
    __syncthreads();

    int anyleft = 1;
    for (int round = 0; round < 700; ++round) {
        // Phase A: kill consumed-column keys; submit survivors
        bool subm[4];
        u64 mybest[4];
        int mycol[4];
        bool anyact = false;
        #pragma unroll
        for (int q = 0; q < 4; ++q) {
            subm[q] = false;
            if (!active[q]) continue;
            u64 best = 0ull;
            #pragma unroll
            for (int k = 0; k < TOPK; ++k) {
                u64 kk = myk[q][k];
                if (kk != 0ull) {
                    int c = key_col(kk);
                    if ((coldone[c >> 5] >> (c & 31)) & 1u) { myk[q][k] = 0ull; kk = 0ull; }
                }
                best = umax64(best, kk);
            }
            if (best == 0ull) { active[q] = false; exh_flag = 1; continue; }
            subm[q] = true;
            mybest[q] = best;
            mycol[q] = key_col(best);
            anyact = true;
            #pragma unroll
            for (int k = 0; k < TOPK; ++k) {
                u64 kk = myk[q][k];
                if (kk != 0ull) atomicMax(&colbest[key_col(kk)], kk);
            }
        }
        anyleft = __syncthreads_count(anyact ? 1 : 0);
        if (anyleft == 0) break;
        // Phase B: commit dominant edges (row-best == col-best)
        #pragma unroll
        for (int q = 0; q < 4; ++q) {
            if (subm[q] && active[q] && colbest[mycol[q]] == mybest[q]) {
                int rr = t + q * 256;
                act[rr] = (float)mycol[q];
                atomicOr(&coldone[mycol[q] >> 5], 1u << (mycol[q] & 31));
                atomicOr(&rowdone[rr >> 5], 1u << (rr & 31));
                active[q] = false;
            }
        }
        __syncthreads();
        // Phase C: clear this round's submissions
        #pragma unroll
        for (int q = 0; q < 4; ++q) {
            if (!subm[q]) continue;
            #pragma unroll
            for (int k = 0; k < TOPK; ++k) {
                u64 kk = myk[q][k];
                if (kk != 0ull) colbest[key_col(kk)] = 0ull;
            }
        }
        __syncthreads();
    }
    __syncthreads();

    // ---- exact-greedy fallback for exhausted rows (P ~ 3e-5): wave 0 ----
    if ((exh_flag || anyleft) && t < 64) {
        int lane = t;
        for (int guard = 0; guard < 1200; ++guard) {
            u64 best = 0ull;
            for (int rr = 0; rr < MROWS; ++rr) {
                if ((rowdone[rr >> 5] >> (rr & 31)) & 1u) continue;
                const float* prow = policy + (size_t)rr * NCOLS;
                u64 rp = (u64)(MROWS - 1 - rr) << 12;
                for (int c = lane; c < NCOLS; c += 64) {
                    if ((coldone[c >> 5] >> (c & 31)) & 1u) continue;
                    u64 kk = ((u64)__float_as_uint(prow[c]) << 22) | rp |
                             (u64)(NCOLS - 1 - c);
                    best = umax64(best, kk);
                }
            }
            best = wave_max_u64(best);
            if (best == 0ull) break;
            if (lane == 0) {
                int row = key_row(best), col = key_col(best);
                rowdone[row >> 5] |= 1u << (row & 31);
                coldone[col >> 5] |= 1u << (col & 31);
                act[row] = (float)col;
            }
            WAVE_FENCE();
        }
    }
    __syncthreads();
    #pragma unroll
    for (int q = 0; q < 4; ++q) {
        int rr = t + q * 256;
        actions[rr] = act[rr];
    }
}

extern "C" void kernel_launch(void* const* d_in, const int* in_sizes, int n_in,
                              void* d_out, int out_size, void* d_ws, size_t ws_size,
                              hipStream_t stream) {
    (void)in_sizes; (void)n_in; (void)out_size; (void)ws_size;
    const float* scores = (const float*)d_in[0];
    const int* cont = (const int*)d_in[1];
    const int* prev = (const int*)d_in[2];
    float* out = (float*)d_out;
    float* actions = out;
    float* policy = out + MROWS;

    char* ws = (char*)d_ws;
    float* bsum = (float*)(ws + 0);              // 256 f
    unsigned* bitmap = (unsigned*)(ws + 2304);   // 128 u32
    unsigned* counter = (unsigned*)(ws + 3072);  // 1 u32
    u64* keys8 = (u64*)(ws + 4096);              // 8192 u64

    k_sum<<<256, 256, 0, stream>>>(scores, bsum, bitmap, counter, cont, prev);
    k_fused<<<MROWS, 256, 0, stream>>>(scores, bsum, bitmap, cont, prev,
                                       policy, keys8, counter, actions);
}